// Round 2
// baseline (118.411 us; speedup 1.0000x reference)
//
#include <hip/hip_runtime.h>
#include <math.h>

#define H      128
#define FCN    400
#define L1N    500
#define L2N    63
#define STEPS  65536

#define NBLK   32
#define TPB    256
#define NWAVES (NBLK * TPB / 64)   // 128 waves total

__device__ __forceinline__ float sigmoidf_(float v) {
    return 1.0f / (1.0f + expf(-v));
}

__device__ __forceinline__ float wave_reduce(float v) {
#pragma unroll
    for (int off = 32; off > 0; off >>= 1)
        v += __shfl_down(v, off, 64);
    return v;
}

// Inter-block barrier: one counter per barrier site (no reuse -> no
// generation/sense needed; counters are zeroed by a hipMemsetAsync before
// launch). Device-scope release on arrive, acquire on the spin load, so
// prior global stores are visible across XCDs (per-XCD L2s not coherent).
__device__ __forceinline__ void grid_barrier(unsigned int* counter) {
    __syncthreads();
    if (threadIdx.x == 0) {
        __threadfence();  // release all prior global writes, device scope
        __hip_atomic_fetch_add(counter, 1u, __ATOMIC_RELEASE,
                               __HIP_MEMORY_SCOPE_AGENT);
        while (__hip_atomic_load(counter, __ATOMIC_ACQUIRE,
                                 __HIP_MEMORY_SCOPE_AGENT) < (unsigned)NBLK) {
            __builtin_amdgcn_s_sleep(1);  // back off the L2 atomic polling
        }
    }
    __syncthreads();
}

// One wave per h-row r (128 rows, 128 waves). i,g,o gate dots (K=128,
// float2/lane). h0=c0=0 -> f gate irrelevant, W_hh contributes nothing.
__device__ __forceinline__ void lstm_stage(
    int gwave, int lane,
    const float* __restrict__ x,    // [H]
    const float* __restrict__ W,    // [4H, H] this layer
    const float* __restrict__ bi,   // [4H]
    const float* __restrict__ bh,   // [4H]
    float* __restrict__ h)          // [H]
{
    const int r = gwave;
    if (r < H) {
        const float2 xv = ((const float2*)x)[lane];
        const float2 a = ((const float2*)(W + (size_t)(0 * H + r) * H))[lane];
        const float2 b = ((const float2*)(W + (size_t)(2 * H + r) * H))[lane];
        const float2 c = ((const float2*)(W + (size_t)(3 * H + r) * H))[lane];
        float pi = fmaf(a.x, xv.x, a.y * xv.y);
        float pg = fmaf(b.x, xv.x, b.y * xv.y);
        float po = fmaf(c.x, xv.x, c.y * xv.y);
        pi = wave_reduce(pi);
        pg = wave_reduce(pg);
        po = wave_reduce(po);
        if (lane == 0) {
            const float ig = pi + bi[0 * H + r] + bh[0 * H + r];
            const float gg = pg + bi[2 * H + r] + bh[2 * H + r];
            const float og = po + bi[3 * H + r] + bh[3 * H + r];
            const float cc = sigmoidf_(ig) * tanhf(gg);
            h[r] = sigmoidf_(og) * tanhf(cc);
        }
    }
}

// One wave per output row, rows strided by NWAVES; K multiple of 4.
__device__ __forceinline__ void mv_stage(
    int gwave, int lane,
    const float* __restrict__ x,   // [K]
    const float* __restrict__ W,   // [N, K]
    const float* __restrict__ b,   // [N]
    float* __restrict__ y,         // [N]
    int N, int K)
{
    const float4* x4 = (const float4*)x;
    const int K4 = K >> 2;
    for (int r = gwave; r < N; r += NWAVES) {
        const float4* w4 = (const float4*)(W + (size_t)r * K);
        float acc = 0.f;
        for (int k = lane; k < K4; k += 64) {
            const float4 a = w4[k];
            const float4 v = x4[k];
            acc = fmaf(a.x, v.x, acc);
            acc = fmaf(a.y, v.y, acc);
            acc = fmaf(a.z, v.z, acc);
            acc = fmaf(a.w, v.w, acc);
        }
        acc = wave_reduce(acc);
        if (lane == 0) y[r] = acc + b[r];
    }
}

// ws layout (floats): [0..31]  barrier counters (5 used, memset to 0)
//                     [64]     h0 (128)
//                     [192]    h1 (128)
//                     [320]    h2 (128)
//                     [448]    fc_o (400)
//                     [848]    l1_o (500)
__global__ __launch_bounds__(TPB) void fused_kernel(
    const float* __restrict__ x_last,
    const float* __restrict__ W_ih,   // [3, 4H, H]
    const float* __restrict__ b_ih,   // [3, 4H]
    const float* __restrict__ b_hh,   // [3, 4H]
    const float* __restrict__ W_fc, const float* __restrict__ b_fc,
    const float* __restrict__ W_l1, const float* __restrict__ b_l1,
    const float* __restrict__ W_l2, const float* __restrict__ b_l2,
    float* __restrict__ out,
    float* __restrict__ ws)
{
    unsigned int* counters = (unsigned int*)ws;
    float* h0   = ws + 64;
    float* h1   = ws + 192;
    float* h2   = ws + 320;
    float* fc_o = ws + 448;
    float* l1_o = ws + 848;

    const int lane  = threadIdx.x & 63;
    const int gwave = blockIdx.x * (TPB / 64) + (threadIdx.x >> 6);

    lstm_stage(gwave, lane, x_last, W_ih, b_ih, b_hh, h0);
    grid_barrier(&counters[0]);
    lstm_stage(gwave, lane, h0, W_ih + 4 * H * H, b_ih + 4 * H, b_hh + 4 * H, h1);
    grid_barrier(&counters[1]);
    lstm_stage(gwave, lane, h1, W_ih + 8 * H * H, b_ih + 8 * H, b_hh + 8 * H, h2);
    grid_barrier(&counters[2]);
    mv_stage(gwave, lane, h2, W_fc, b_fc, fc_o, FCN, H);
    grid_barrier(&counters[3]);
    mv_stage(gwave, lane, fc_o, W_l1, b_l1, l1_o, L1N, FCN);
    grid_barrier(&counters[4]);
    mv_stage(gwave, lane, l1_o, W_l2, b_l2, out, L2N, L1N);
}

extern "C" void kernel_launch(void* const* d_in, const int* in_sizes, int n_in,
                              void* d_out, int out_size, void* d_ws, size_t ws_size,
                              hipStream_t stream) {
    const float* inputs = (const float*)d_in[0];
    const float* W_ih   = (const float*)d_in[1];
    // d_in[2] = W_hh (unused: h0 = 0)
    const float* b_ih   = (const float*)d_in[3];
    const float* b_hh   = (const float*)d_in[4];
    const float* W_fc   = (const float*)d_in[5];
    const float* b_fc   = (const float*)d_in[6];
    const float* W_l1   = (const float*)d_in[7];
    const float* b_l1   = (const float*)d_in[8];
    const float* W_l2   = (const float*)d_in[9];
    const float* b_l2   = (const float*)d_in[10];
    float* out = (float*)d_out;
    float* ws  = (float*)d_ws;

    const float* x_last = inputs + (size_t)(STEPS - 1) * H;

    // Zero the barrier counters (workspace may be poisoned per-iteration).
    hipMemsetAsync(ws, 0, 128, stream);

    fused_kernel<<<NBLK, TPB, 0, stream>>>(
        x_last, W_ih, b_ih, b_hh, W_fc, b_fc, W_l1, b_l1, W_l2, b_l2, out, ws);
}